// Round 7
// baseline (323.065 us; speedup 1.0000x reference)
//
#include <hip/hip_runtime.h>
#include <hip/hip_bf16.h>
#include <math.h>

#define L_    4096
#define C96   96
#define DI_   192
#define Nn    16
#define Rr    6
#define Kk    4
#define HW_   64
#define HF_   255

__device__ __forceinline__ float sp_softplus(float s) {
    return fmaxf(s, 0.f) + log1pf(expf(-fabsf(s)));
}
__device__ __forceinline__ float sp_silu(float s) {
    return s / (1.f + expf(-s));
}
// quad-perm DPP shuffles (full-rate VALU, lanes within quad)
__device__ __forceinline__ float qxor1(float x) {
    return __int_as_float(__builtin_amdgcn_update_dpp(0, __float_as_int(x),
                                                      0xB1, 0xF, 0xF, true));
}
__device__ __forceinline__ float qxor2(float x) {
    return __int_as_float(__builtin_amdgcn_update_dpp(0, __float_as_int(x),
                                                      0x4E, 0xF, 0xF, true));
}

// K1: RMS-LN, l-tile=16, 16 groups x 6 channels. grid=256.
__global__ __launch_bounds__(256) void k_rmsln1(const float* __restrict__ x,
        const float* __restrict__ w, const float* __restrict__ b,
        float* __restrict__ n1) {
    __shared__ float red[16][16];
    int l0 = blockIdx.x * 16;
    int t = threadIdx.x;
    int l = t & 15, g = t >> 4;
    float xv[6];
    float ss = 0.f;
#pragma unroll
    for (int j = 0; j < 6; ++j) {
        int c = g * 6 + j;
        xv[j] = x[c * L_ + l0 + l];
        ss += xv[j] * xv[j];
    }
    red[g][l] = ss;
    __syncthreads();
    float tot = 0.f;
#pragma unroll
    for (int g2 = 0; g2 < 16; ++g2) tot += red[g2][l];
    float r = rsqrtf(tot * (1.f / C96) + 1e-6f);
#pragma unroll
    for (int j = 0; j < 6; ++j) {
        int c = g * 6 + j;
        n1[c * L_ + l0 + l] = xv[j] * r * w[c] + b[c];
    }
}

// K2v2: in_proj GEMM, LDS-staged. grid (64, 6), block 256 = 64 l x 4 og,
// 16 o/thread. W rows wave-uniform -> scalar loads.
__global__ __launch_bounds__(256) void k_inproj2(const float* __restrict__ n1,
        const float* __restrict__ W, float* __restrict__ xzT) {
    __shared__ float sx[C96][64];
    int l0 = blockIdx.x * 64;
    int t = threadIdx.x;
    for (int i = t; i < C96 * 64; i += 256) {
        int c = i >> 6, l = i & 63;
        sx[c][l] = n1[c * L_ + l0 + l];
    }
    __syncthreads();
    int l = t & 63, og = t >> 6;
    int o0 = blockIdx.y * 64 + og * 16;
    float acc[16];
#pragma unroll
    for (int j = 0; j < 16; ++j) acc[j] = 0.f;
    for (int c = 0; c < C96; ++c) {
        float v = sx[c][l];
#pragma unroll
        for (int j = 0; j < 16; ++j) acc[j] += v * W[(o0 + j) * C96 + c];
    }
#pragma unroll
    for (int j = 0; j < 16; ++j) xzT[(o0 + j) * L_ + l0 + l] = acc[j];
}

// K3: depthwise 3x3 conv (SAME) + bias + SiLU on xc (192, 64, 64).
__global__ void k_conv192(const float* __restrict__ xc, const float* __restrict__ w,
                          const float* __restrict__ b, float* __restrict__ out) {
    int idx = blockIdx.x * 256 + threadIdx.x;
    if (idx >= DI_ * L_) return;
    int c = idx / L_, l = idx % L_;
    int h = l >> 6, wc = l & 63;
    float s = b[c];
#pragma unroll
    for (int di = -1; di <= 1; ++di)
#pragma unroll
        for (int dj = -1; dj <= 1; ++dj) {
            int hh = h + di, ww = wc + dj;
            if (hh >= 0 && hh < HW_ && ww >= 0 && ww < HW_)
                s += xc[c * L_ + hh * HW_ + ww] * w[c * 9 + (di + 1) * 3 + (dj + 1)];
        }
    out[idx] = sp_silu(s);
}

// K4: materialize 4 direction views xs[(k*DI+d)*L + l]
__global__ void k_build_xs(const float* __restrict__ xconv, float* __restrict__ xs) {
    int idx = blockIdx.x * 256 + threadIdx.x;
    if (idx >= Kk * DI_ * L_) return;
    int l = idx % L_; int kd = idx / L_; int d = kd % DI_; int k = kd / DI_;
    int ll = (k & 2) ? (L_ - 1 - l) : l;
    int pos = (k & 1) ? ((ll & 63) * 64 + (ll >> 6)) : ll;
    xs[idx] = xconv[d * L_ + pos];
}

// K5: x_proj GEMM fused with B/C transpose. Block=256: one k, 64-wide l tile.
__global__ __launch_bounds__(256) void k_xdbl2(const float* __restrict__ xs,
        const float* __restrict__ Wxp, float* __restrict__ dts,
        float* __restrict__ BsT, float* __restrict__ CsT) {
    __shared__ float sx[DI_][64];
    int k = blockIdx.y;
    int l0 = blockIdx.x * 64;
    int t = threadIdx.x;
    const float* src = xs + (k * DI_) * L_ + l0;
    for (int i = t; i < DI_ * 64; i += 256) {
        int d = i >> 6, l = i & 63;
        sx[d][l] = src[d * L_ + l];
    }
    __syncthreads();
    int l = t & 63, cg = t >> 6;
    int c0 = cg * 10;
    int cnt = (cg == 3) ? 8 : 10;
    float acc[10] = {0.f, 0.f, 0.f, 0.f, 0.f, 0.f, 0.f, 0.f, 0.f, 0.f};
    const float* Wk = Wxp + k * 38 * DI_;
    for (int d = 0; d < DI_; ++d) {
        float v = sx[d][l];
#pragma unroll
        for (int j = 0; j < 10; ++j) {
            int cj = c0 + j; if (cj > 37) cj = 37;
            acc[j] += v * Wk[cj * DI_ + d];
        }
    }
    int gl = l0 + l;
#pragma unroll
    for (int j = 0; j < 10; ++j) {
        if (j < cnt) {
            int c = c0 + j;
            float v = acc[j];
            if (c < Rr)           dts[(k * Rr + c) * L_ + gl] = v;
            else if (c < Rr + Nn) BsT[(k * L_ + gl) * Nn + (c - Rr)] = v;
            else                  CsT[(k * L_ + gl) * Nn + (c - Rr - Nn)] = v;
        }
    }
}

// K6: delta[kd, l] = softplus(sum_r dts[k,r,l] * dtw[kd,r] + dtb[kd])
__global__ void k_delta(const float* __restrict__ dts, const float* __restrict__ dtw,
                        const float* __restrict__ dtb, float* __restrict__ delta) {
    int idx = blockIdx.x * 256 + threadIdx.x;
    if (idx >= Kk * DI_ * L_) return;
    int l = idx % L_; int kd = idx / L_; int k = kd / DI_;
    float s = dtb[kd];
#pragma unroll
    for (int r = 0; r < Rr; ++r)
        s += dts[(k * Rr + r) * L_ + l] * dtw[kd * Rr + r];
    delta[idx] = sp_softplus(s);
}

// K8: FUSED selective scan. One block per kd (grid=768, 256 thr).
__global__ __launch_bounds__(256) void k_scan(const float* __restrict__ delta,
        const float* __restrict__ xs, const float* __restrict__ BsT,
        const float* __restrict__ CsT, const float* __restrict__ A_logs,
        const float* __restrict__ Ds, float* __restrict__ scan_y) {
    __shared__ float dl_s[64 * 65];
    __shared__ float u_s[64 * 65];
    __shared__ float ys[64 * 65];
    __shared__ float Pl[64][16];
    __shared__ float Sl[64][16];
    int kd = blockIdx.x; int k = kd / DI_;
    int t = threadIdx.x;
    {
        const float4* dg = (const float4*)(delta + kd * L_);
        const float4* ug = (const float4*)(xs + kd * L_);
        for (int s = t; s < 1024; s += 256) {
            float4 dv = dg[s], uv = ug[s];
            int o = (s >> 4) * 65 + ((s << 2) & 63);
            dl_s[o] = dv.x; dl_s[o + 1] = dv.y; dl_s[o + 2] = dv.z; dl_s[o + 3] = dv.w;
            u_s[o] = uv.x;  u_s[o + 1] = uv.y;  u_s[o + 2] = uv.z;  u_s[o + 3] = uv.w;
        }
    }
    int g = t >> 2, j = t & 3;
    float4 Al = *(const float4*)&A_logs[kd * Nn + 4 * j];
    float A0 = -__expf(Al.x), A1 = -__expf(Al.y), A2 = -__expf(Al.z), A3 = -__expf(Al.w);
    __syncthreads();
    int lo = g * 65;
    const float4* Bv = (const float4*)&BsT[(k * L_ + g * 64) * Nn + 4 * j];
    const float4* Cv = (const float4*)&CsT[(k * L_ + g * 64) * Nn + 4 * j];
    float h0 = 0.f, h1 = 0.f, h2 = 0.f, h3 = 0.f;
    float p0 = 1.f, p1 = 1.f, p2 = 1.f, p3 = 1.f;
    for (int i = 0; i < 64; ++i) {
        float dl = dl_s[lo + i], ul = u_s[lo + i];
        float4 bv = Bv[i * 4];
        float du = dl * ul;
        float e0 = __expf(dl * A0), e1 = __expf(dl * A1);
        float e2 = __expf(dl * A2), e3 = __expf(dl * A3);
        h0 = e0 * h0 + du * bv.x; h1 = e1 * h1 + du * bv.y;
        h2 = e2 * h2 + du * bv.z; h3 = e3 * h3 + du * bv.w;
        p0 *= e0; p1 *= e1; p2 *= e2; p3 *= e3;
    }
    *(float4*)&Pl[g][4 * j] = make_float4(p0, p1, p2, p3);
    *(float4*)&Sl[g][4 * j] = make_float4(h0, h1, h2, h3);
    __syncthreads();
    for (int s = 1; s < 64; s <<= 1) {
        float4 pp, sp;
        bool act = (g >= s);
        if (act) {
            pp = *(float4*)&Pl[g - s][4 * j];
            sp = *(float4*)&Sl[g - s][4 * j];
        }
        __syncthreads();
        if (act) {
            float4 pc = *(float4*)&Pl[g][4 * j];
            float4 sc = *(float4*)&Sl[g][4 * j];
            *(float4*)&Pl[g][4 * j] =
                make_float4(pp.x * pc.x, pp.y * pc.y, pp.z * pc.z, pp.w * pc.w);
            *(float4*)&Sl[g][4 * j] =
                make_float4(pc.x * sp.x + sc.x, pc.y * sp.y + sc.y,
                            pc.z * sp.z + sc.z, pc.w * sp.w + sc.w);
        }
        __syncthreads();
    }
    float4 hv = make_float4(0.f, 0.f, 0.f, 0.f);
    if (g > 0) hv = *(const float4*)&Sl[g - 1][4 * j];
    float Dp = Ds[kd];
    h0 = hv.x; h1 = hv.y; h2 = hv.z; h3 = hv.w;
    for (int i = 0; i < 64; ++i) {
        float dl = dl_s[lo + i], ul = u_s[lo + i];
        float4 bv = Bv[i * 4];
        float4 cv = Cv[i * 4];
        float du = dl * ul;
        float e0 = __expf(dl * A0), e1 = __expf(dl * A1);
        float e2 = __expf(dl * A2), e3 = __expf(dl * A3);
        h0 = e0 * h0 + du * bv.x; h1 = e1 * h1 + du * bv.y;
        h2 = e2 * h2 + du * bv.z; h3 = e3 * h3 + du * bv.w;
        float ps = h0 * cv.x + h1 * cv.y + h2 * cv.z + h3 * cv.w;
        ps += qxor1(ps);
        ps += qxor2(ps);
        if (j == 0) ys[lo + i] = ps + Dp * ul;
    }
    __syncthreads();
    float* yout = scan_y + kd * L_;
    for (int p = t; p < L_; p += 256) {
        int ll = (k & 1) ? (((p & 63) << 6) | (p >> 6)) : p;
        int sl = (k & 2) ? (L_ - 1 - ll) : ll;
        yout[p] = ys[sl + (sl >> 6)];
    }
}

// K11: l-tile=16, grid=256 blocks, 256 threads = 16 groups x 16 lanes.
__global__ __launch_bounds__(256) void k_combine3(
        const float* __restrict__ scan_y, const float* __restrict__ onw,
        const float* __restrict__ onb, const float* __restrict__ xzT,
        const float* __restrict__ Wout, const float* __restrict__ x,
        const float* __restrict__ w2, const float* __restrict__ b2,
        float* __restrict__ x2, float* __restrict__ n2) {
    __shared__ float yt[16][196];
    __shared__ float red[16][16];
    int l0 = blockIdx.x * 16;
    int t = threadIdx.x;
    int l = t & 15, g = t >> 4;
    int d0 = g * 12;
    float psum = 0.f;
#pragma unroll
    for (int j = 0; j < 12; ++j) {
        int d = d0 + j;
        float y = scan_y[(0 * DI_ + d) * L_ + l0 + l]
                + scan_y[(1 * DI_ + d) * L_ + l0 + l]
                + scan_y[(2 * DI_ + d) * L_ + l0 + l]
                + scan_y[(3 * DI_ + d) * L_ + l0 + l];
        yt[l][d] = y;
        psum += y;
    }
    red[g][l] = psum;
    __syncthreads();
    float mu = 0.f;
#pragma unroll
    for (int g2 = 0; g2 < 16; ++g2) mu += red[g2][l];
    mu *= (1.f / DI_);
    float pv = 0.f;
#pragma unroll
    for (int j = 0; j < 12; ++j) {
        float yc = yt[l][d0 + j] - mu;
        pv += yc * yc;
    }
    __syncthreads();
    red[g][l] = pv;
    __syncthreads();
    float var = 0.f;
#pragma unroll
    for (int g2 = 0; g2 < 16; ++g2) var += red[g2][l];
    var *= (1.f / DI_);
    float rstd = rsqrtf(var + 1e-5f);
#pragma unroll
    for (int j = 0; j < 12; ++j) {
        int d = d0 + j;
        float zv = xzT[(DI_ + d) * L_ + l0 + l];
        float yn = (yt[l][d] - mu) * rstd * onw[d] + onb[d];
        yt[l][d] = yn * sp_silu(zv);
    }
    __syncthreads();
    int c0 = g * 6;
    float acc[6] = {0.f, 0.f, 0.f, 0.f, 0.f, 0.f};
    for (int dd = 0; dd < DI_; dd += 4) {
        float4 yv = *(const float4*)&yt[l][dd];
#pragma unroll
        for (int j = 0; j < 6; ++j) {
            float4 wv = *(const float4*)&Wout[(c0 + j) * DI_ + dd];
            acc[j] += yv.x * wv.x + yv.y * wv.y + yv.z * wv.z + yv.w * wv.w;
        }
    }
    float ss = 0.f;
    float x2v[6];
#pragma unroll
    for (int j = 0; j < 6; ++j) {
        int c = c0 + j;
        float v = x[c * L_ + l0 + l] + acc[j];
        x2v[j] = v; ss += v * v;
        x2[c * L_ + l0 + l] = v;
    }
    __syncthreads();
    red[g][l] = ss;
    __syncthreads();
    float tot = 0.f;
#pragma unroll
    for (int g2 = 0; g2 < 16; ++g2) tot += red[g2][l];
    float r2 = rsqrtf(tot * (1.f / C96) + 1e-6f);
#pragma unroll
    for (int j = 0; j < 6; ++j) {
        int c = c0 + j;
        n2[c * L_ + l0 + l] = x2v[j] * r2 * w2[c] + b2[c];
    }
}

// K12v2: EDFFN pin GEMM, LDS-staged. grid (64, 8), 16 o/thread, clamp at 510.
__global__ __launch_bounds__(256) void k_pin2(const float* __restrict__ n2,
        const float* __restrict__ W, float* __restrict__ hf) {
    __shared__ float sx[C96][64];
    int l0 = blockIdx.x * 64;
    int t = threadIdx.x;
    for (int i = t; i < C96 * 64; i += 256) {
        int c = i >> 6, l = i & 63;
        sx[c][l] = n2[c * L_ + l0 + l];
    }
    __syncthreads();
    int l = t & 63, og = t >> 6;
    int o0 = blockIdx.y * 64 + og * 16;
    float acc[16];
#pragma unroll
    for (int j = 0; j < 16; ++j) acc[j] = 0.f;
    for (int c = 0; c < C96; ++c) {
        float v = sx[c][l];
#pragma unroll
        for (int j = 0; j < 16; ++j) {
            int oj = o0 + j; if (oj > 509) oj = 509;   // clamp keeps loads uniform
            acc[j] += v * W[oj * C96 + c];
        }
    }
#pragma unroll
    for (int j = 0; j < 16; ++j) {
        int o = o0 + j;
        if (o < 510) hf[o * L_ + l0 + l] = acc[j];
    }
}

// K13: depthwise 3x3 (no bias) on 510 channels + GELU(h1)*h2 gate.
__global__ void k_ffnconv(const float* __restrict__ hf, const float* __restrict__ w,
                          float* __restrict__ g) {
    int idx = blockIdx.x * 256 + threadIdx.x;
    if (idx >= HF_ * L_) return;
    int c = idx / L_, l = idx % L_;
    int h = l >> 6, wc = l & 63;
    float s1 = 0.f, s2 = 0.f;
#pragma unroll
    for (int di = -1; di <= 1; ++di)
#pragma unroll
        for (int dj = -1; dj <= 1; ++dj) {
            int hh = h + di, ww = wc + dj;
            if (hh >= 0 && hh < HW_ && ww >= 0 && ww < HW_) {
                int p = hh * HW_ + ww;
                int widx = (di + 1) * 3 + (dj + 1);
                s1 += hf[c * L_ + p] * w[c * 9 + widx];
                s2 += hf[(c + HF_) * L_ + p] * w[(c + HF_) * 9 + widx];
            }
        }
    float ge = 0.5f * s1 * (1.f + erff(s1 * 0.70710678118654752f));
    g[idx] = ge * s2;
}

// K14v2: pout GEMM + residual, LDS-staged in 3 c-chunks of 85. grid (64, 2),
// 12 c/thread.
__global__ __launch_bounds__(256) void k_pout2(const float* __restrict__ g,
        const float* __restrict__ W, const float* __restrict__ x2,
        float* __restrict__ out) {
    __shared__ float sg[85][64];
    int l0 = blockIdx.x * 64;
    int t = threadIdx.x;
    int l = t & 63, og = t >> 6;
    int c0 = blockIdx.y * 48 + og * 12;
    float acc[12];
#pragma unroll
    for (int j = 0; j < 12; ++j) acc[j] = 0.f;
    for (int ch = 0; ch < 3; ++ch) {
        int cc0 = ch * 85;
        __syncthreads();
        for (int i = t; i < 85 * 64; i += 256) {
            int c = i >> 6, ll = i & 63;
            sg[c][ll] = g[(cc0 + c) * L_ + l0 + ll];
        }
        __syncthreads();
        for (int c = 0; c < 85; ++c) {
            float v = sg[c][l];
#pragma unroll
            for (int j = 0; j < 12; ++j)
                acc[j] += v * W[(c0 + j) * HF_ + cc0 + c];
        }
    }
#pragma unroll
    for (int j = 0; j < 12; ++j) {
        int c = c0 + j;
        out[c * L_ + l0 + l] = x2[c * L_ + l0 + l] + acc[j];
    }
}

extern "C" void kernel_launch(void* const* d_in, const int* in_sizes, int n_in,
                              void* d_out, int out_size, void* d_ws, size_t ws_size,
                              hipStream_t stream) {
    const float* x         = (const float*)d_in[0];
    const float* norm1_w   = (const float*)d_in[1];
    const float* norm1_b   = (const float*)d_in[2];
    const float* in_proj_w = (const float*)d_in[3];
    const float* conv2d_w  = (const float*)d_in[4];
    const float* conv2d_b  = (const float*)d_in[5];
    const float* x_proj_w  = (const float*)d_in[6];
    const float* dt_projs_w= (const float*)d_in[7];
    const float* dt_projs_b= (const float*)d_in[8];
    const float* A_logs    = (const float*)d_in[9];
    const float* Ds        = (const float*)d_in[10];
    const float* out_norm_w= (const float*)d_in[11];
    const float* out_norm_b= (const float*)d_in[12];
    const float* out_proj_w= (const float*)d_in[13];
    const float* norm2_w   = (const float*)d_in[14];
    const float* norm2_b   = (const float*)d_in[15];
    const float* pin_w     = (const float*)d_in[16];
    const float* dw_w      = (const float*)d_in[17];
    const float* pout_w    = (const float*)d_in[18];

    float* ws = (float*)d_ws;
    float* n1     = ws; ws += C96 * L_;          // reused as dtsb after inproj
    float* xzT    = ws; ws += 2 * DI_ * L_;
    float* xconv  = ws; ws += DI_ * L_;
    float* xs     = ws; ws += Kk * DI_ * L_;     // reused as hf after scan
    float* delta  = ws; ws += Kk * DI_ * L_;     // reused as gbuf after scan
    float* BsT    = ws; ws += Kk * L_ * Nn;
    float* CsT    = ws; ws += Kk * L_ * Nn;
    float* scan_y = ws; ws += Kk * DI_ * L_;
    float* x2     = ws; ws += C96 * L_;
    float* n2     = ws; ws += C96 * L_;
    float* dtsb   = n1;
    float* hf     = xs;
    float* gbuf   = delta;

    k_rmsln1<<<256, 256, 0, stream>>>(x, norm1_w, norm1_b, n1);
    k_inproj2<<<dim3(64, 6), 256, 0, stream>>>(n1, in_proj_w, xzT);
    k_conv192<<<3072, 256, 0, stream>>>(xzT, conv2d_w, conv2d_b, xconv);
    k_build_xs<<<12288, 256, 0, stream>>>(xconv, xs);
    k_xdbl2<<<dim3(64, 4), 256, 0, stream>>>(xs, x_proj_w, dtsb, BsT, CsT);
    k_delta<<<12288, 256, 0, stream>>>(dtsb, dt_projs_w, dt_projs_b, delta);
    k_scan<<<768, 256, 0, stream>>>(delta, xs, BsT, CsT, A_logs, Ds, scan_y);
    k_combine3<<<256, 256, 0, stream>>>(scan_y, out_norm_w, out_norm_b, xzT,
                                        out_proj_w, x, norm2_w, norm2_b, x2, n2);
    k_pin2<<<dim3(64, 8), 256, 0, stream>>>(n2, pin_w, hf);
    k_ffnconv<<<4080, 256, 0, stream>>>(hf, dw_w, gbuf);
    k_pout2<<<dim3(64, 2), 256, 0, stream>>>(gbuf, pout_w, x2, (float*)d_out);
}

// Round 8
// 270.619 us; speedup vs baseline: 1.1938x; 1.1938x over previous
//
#include <hip/hip_runtime.h>
#include <hip/hip_bf16.h>
#include <math.h>

#define L_    4096
#define C96   96
#define DI_   192
#define Nn    16
#define Rr    6
#define Kk    4
#define HW_   64
#define HF_   255

__device__ __forceinline__ float sp_softplus(float s) {
    return fmaxf(s, 0.f) + log1pf(expf(-fabsf(s)));
}
__device__ __forceinline__ float sp_silu(float s) {
    return s / (1.f + expf(-s));
}
// quad-perm DPP shuffles (full-rate VALU, lanes within quad)
__device__ __forceinline__ float qxor1(float x) {
    return __int_as_float(__builtin_amdgcn_update_dpp(0, __float_as_int(x),
                                                      0xB1, 0xF, 0xF, true));
}
__device__ __forceinline__ float qxor2(float x) {
    return __int_as_float(__builtin_amdgcn_update_dpp(0, __float_as_int(x),
                                                      0x4E, 0xF, 0xF, true));
}

// K1: RMS-LN, l-tile=16, 16 groups x 6 channels. grid=256.
__global__ __launch_bounds__(256) void k_rmsln1(const float* __restrict__ x,
        const float* __restrict__ w, const float* __restrict__ b,
        float* __restrict__ n1) {
    __shared__ float red[16][16];
    int l0 = blockIdx.x * 16;
    int t = threadIdx.x;
    int l = t & 15, g = t >> 4;
    float xv[6];
    float ss = 0.f;
#pragma unroll
    for (int j = 0; j < 6; ++j) {
        int c = g * 6 + j;
        xv[j] = x[c * L_ + l0 + l];
        ss += xv[j] * xv[j];
    }
    red[g][l] = ss;
    __syncthreads();
    float tot = 0.f;
#pragma unroll
    for (int g2 = 0; g2 < 16; ++g2) tot += red[g2][l];
    float r = rsqrtf(tot * (1.f / C96) + 1e-6f);
#pragma unroll
    for (int j = 0; j < 6; ++j) {
        int c = g * 6 + j;
        n1[c * L_ + l0 + l] = xv[j] * r * w[c] + b[c];
    }
}

// K2: in_proj GEMM, LDS-staged. grid (64, 6), 16 o/thread.
__global__ __launch_bounds__(256) void k_inproj2(const float* __restrict__ n1,
        const float* __restrict__ W, float* __restrict__ xzT) {
    __shared__ float sx[C96][64];
    int l0 = blockIdx.x * 64;
    int t = threadIdx.x;
    for (int i = t; i < C96 * 64; i += 256) {
        int c = i >> 6, l = i & 63;
        sx[c][l] = n1[c * L_ + l0 + l];
    }
    __syncthreads();
    int l = t & 63, og = t >> 6;
    int o0 = blockIdx.y * 64 + og * 16;
    float acc[16];
#pragma unroll
    for (int j = 0; j < 16; ++j) acc[j] = 0.f;
    for (int c = 0; c < C96; ++c) {
        float v = sx[c][l];
#pragma unroll
        for (int j = 0; j < 16; ++j) acc[j] += v * W[(o0 + j) * C96 + c];
    }
#pragma unroll
    for (int j = 0; j < 16; ++j) xzT[(o0 + j) * L_ + l0 + l] = acc[j];
}

// K3: depthwise 3x3 conv (SAME) + bias + SiLU on xc (192, 64, 64).
__global__ void k_conv192(const float* __restrict__ xc, const float* __restrict__ w,
                          const float* __restrict__ b, float* __restrict__ out) {
    int idx = blockIdx.x * 256 + threadIdx.x;
    if (idx >= DI_ * L_) return;
    int c = idx / L_, l = idx % L_;
    int h = l >> 6, wc = l & 63;
    float s = b[c];
#pragma unroll
    for (int di = -1; di <= 1; ++di)
#pragma unroll
        for (int dj = -1; dj <= 1; ++dj) {
            int hh = h + di, ww = wc + dj;
            if (hh >= 0 && hh < HW_ && ww >= 0 && ww < HW_)
                s += xc[c * L_ + hh * HW_ + ww] * w[c * 9 + (di + 1) * 3 + (dj + 1)];
        }
    out[idx] = sp_silu(s);
}

// K4: materialize 4 direction views xs[(k*DI+d)*L + l]
__global__ void k_build_xs(const float* __restrict__ xconv, float* __restrict__ xs) {
    int idx = blockIdx.x * 256 + threadIdx.x;
    if (idx >= Kk * DI_ * L_) return;
    int l = idx % L_; int kd = idx / L_; int d = kd % DI_; int k = kd / DI_;
    int ll = (k & 2) ? (L_ - 1 - l) : l;
    int pos = (k & 1) ? ((ll & 63) * 64 + (ll >> 6)) : ll;
    xs[idx] = xconv[d * L_ + pos];
}

// K5: x_proj GEMM fused with B/C transpose. Block=256: one k, 64-wide l tile.
__global__ __launch_bounds__(256) void k_xdbl2(const float* __restrict__ xs,
        const float* __restrict__ Wxp, float* __restrict__ dts,
        float* __restrict__ BsT, float* __restrict__ CsT) {
    __shared__ float sx[DI_][64];
    int k = blockIdx.y;
    int l0 = blockIdx.x * 64;
    int t = threadIdx.x;
    const float* src = xs + (k * DI_) * L_ + l0;
    for (int i = t; i < DI_ * 64; i += 256) {
        int d = i >> 6, l = i & 63;
        sx[d][l] = src[d * L_ + l];
    }
    __syncthreads();
    int l = t & 63, cg = t >> 6;
    int c0 = cg * 10;
    int cnt = (cg == 3) ? 8 : 10;
    float acc[10] = {0.f, 0.f, 0.f, 0.f, 0.f, 0.f, 0.f, 0.f, 0.f, 0.f};
    const float* Wk = Wxp + k * 38 * DI_;
    for (int d = 0; d < DI_; ++d) {
        float v = sx[d][l];
#pragma unroll
        for (int j = 0; j < 10; ++j) {
            int cj = c0 + j; if (cj > 37) cj = 37;
            acc[j] += v * Wk[cj * DI_ + d];
        }
    }
    int gl = l0 + l;
#pragma unroll
    for (int j = 0; j < 10; ++j) {
        if (j < cnt) {
            int c = c0 + j;
            float v = acc[j];
            if (c < Rr)           dts[(k * Rr + c) * L_ + gl] = v;
            else if (c < Rr + Nn) BsT[(k * L_ + gl) * Nn + (c - Rr)] = v;
            else                  CsT[(k * L_ + gl) * Nn + (c - Rr - Nn)] = v;
        }
    }
}

// K6: delta[kd, l] = softplus(sum_r dts[k,r,l] * dtw[kd,r] + dtb[kd])
__global__ void k_delta(const float* __restrict__ dts, const float* __restrict__ dtw,
                        const float* __restrict__ dtb, float* __restrict__ delta) {
    int idx = blockIdx.x * 256 + threadIdx.x;
    if (idx >= Kk * DI_ * L_) return;
    int l = idx % L_; int kd = idx / L_; int k = kd / DI_;
    float s = dtb[kd];
#pragma unroll
    for (int r = 0; r < Rr; ++r)
        s += dts[(k * Rr + r) * L_ + l] * dtw[kd * Rr + r];
    delta[idx] = sp_softplus(s);
}

// K8: FUSED selective scan. One block per kd (grid=768, 256 thr).
__global__ __launch_bounds__(256) void k_scan(const float* __restrict__ delta,
        const float* __restrict__ xs, const float* __restrict__ BsT,
        const float* __restrict__ CsT, const float* __restrict__ A_logs,
        const float* __restrict__ Ds, float* __restrict__ scan_y) {
    __shared__ float dl_s[64 * 65];
    __shared__ float u_s[64 * 65];
    __shared__ float ys[64 * 65];
    __shared__ float Pl[64][16];
    __shared__ float Sl[64][16];
    int kd = blockIdx.x; int k = kd / DI_;
    int t = threadIdx.x;
    {
        const float4* dg = (const float4*)(delta + kd * L_);
        const float4* ug = (const float4*)(xs + kd * L_);
        for (int s = t; s < 1024; s += 256) {
            float4 dv = dg[s], uv = ug[s];
            int o = (s >> 4) * 65 + ((s << 2) & 63);
            dl_s[o] = dv.x; dl_s[o + 1] = dv.y; dl_s[o + 2] = dv.z; dl_s[o + 3] = dv.w;
            u_s[o] = uv.x;  u_s[o + 1] = uv.y;  u_s[o + 2] = uv.z;  u_s[o + 3] = uv.w;
        }
    }
    int g = t >> 2, j = t & 3;
    float4 Al = *(const float4*)&A_logs[kd * Nn + 4 * j];
    float A0 = -__expf(Al.x), A1 = -__expf(Al.y), A2 = -__expf(Al.z), A3 = -__expf(Al.w);
    __syncthreads();
    int lo = g * 65;
    const float4* Bv = (const float4*)&BsT[(k * L_ + g * 64) * Nn + 4 * j];
    const float4* Cv = (const float4*)&CsT[(k * L_ + g * 64) * Nn + 4 * j];
    float h0 = 0.f, h1 = 0.f, h2 = 0.f, h3 = 0.f;
    float p0 = 1.f, p1 = 1.f, p2 = 1.f, p3 = 1.f;
    for (int i = 0; i < 64; ++i) {
        float dl = dl_s[lo + i], ul = u_s[lo + i];
        float4 bv = Bv[i * 4];
        float du = dl * ul;
        float e0 = __expf(dl * A0), e1 = __expf(dl * A1);
        float e2 = __expf(dl * A2), e3 = __expf(dl * A3);
        h0 = e0 * h0 + du * bv.x; h1 = e1 * h1 + du * bv.y;
        h2 = e2 * h2 + du * bv.z; h3 = e3 * h3 + du * bv.w;
        p0 *= e0; p1 *= e1; p2 *= e2; p3 *= e3;
    }
    *(float4*)&Pl[g][4 * j] = make_float4(p0, p1, p2, p3);
    *(float4*)&Sl[g][4 * j] = make_float4(h0, h1, h2, h3);
    __syncthreads();
    for (int s = 1; s < 64; s <<= 1) {
        float4 pp, sp;
        bool act = (g >= s);
        if (act) {
            pp = *(float4*)&Pl[g - s][4 * j];
            sp = *(float4*)&Sl[g - s][4 * j];
        }
        __syncthreads();
        if (act) {
            float4 pc = *(float4*)&Pl[g][4 * j];
            float4 sc = *(float4*)&Sl[g][4 * j];
            *(float4*)&Pl[g][4 * j] =
                make_float4(pp.x * pc.x, pp.y * pc.y, pp.z * pc.z, pp.w * pc.w);
            *(float4*)&Sl[g][4 * j] =
                make_float4(pc.x * sp.x + sc.x, pc.y * sp.y + sc.y,
                            pc.z * sp.z + sc.z, pc.w * sp.w + sc.w);
        }
        __syncthreads();
    }
    float4 hv = make_float4(0.f, 0.f, 0.f, 0.f);
    if (g > 0) hv = *(const float4*)&Sl[g - 1][4 * j];
    float Dp = Ds[kd];
    h0 = hv.x; h1 = hv.y; h2 = hv.z; h3 = hv.w;
    for (int i = 0; i < 64; ++i) {
        float dl = dl_s[lo + i], ul = u_s[lo + i];
        float4 bv = Bv[i * 4];
        float4 cv = Cv[i * 4];
        float du = dl * ul;
        float e0 = __expf(dl * A0), e1 = __expf(dl * A1);
        float e2 = __expf(dl * A2), e3 = __expf(dl * A3);
        h0 = e0 * h0 + du * bv.x; h1 = e1 * h1 + du * bv.y;
        h2 = e2 * h2 + du * bv.z; h3 = e3 * h3 + du * bv.w;
        float ps = h0 * cv.x + h1 * cv.y + h2 * cv.z + h3 * cv.w;
        ps += qxor1(ps);
        ps += qxor2(ps);
        if (j == 0) ys[lo + i] = ps + Dp * ul;
    }
    __syncthreads();
    float* yout = scan_y + kd * L_;
    for (int p = t; p < L_; p += 256) {
        int ll = (k & 1) ? (((p & 63) << 6) | (p >> 6)) : p;
        int sl = (k & 2) ? (L_ - 1 - ll) : ll;
        yout[p] = ys[sl + (sl >> 6)];
    }
}

// K11: l-tile=16, grid=256 blocks, 256 threads = 16 groups x 16 lanes.
__global__ __launch_bounds__(256) void k_combine3(
        const float* __restrict__ scan_y, const float* __restrict__ onw,
        const float* __restrict__ onb, const float* __restrict__ xzT,
        const float* __restrict__ Wout, const float* __restrict__ x,
        const float* __restrict__ w2, const float* __restrict__ b2,
        float* __restrict__ x2, float* __restrict__ n2) {
    __shared__ float yt[16][196];
    __shared__ float red[16][16];
    int l0 = blockIdx.x * 16;
    int t = threadIdx.x;
    int l = t & 15, g = t >> 4;
    int d0 = g * 12;
    float psum = 0.f;
#pragma unroll
    for (int j = 0; j < 12; ++j) {
        int d = d0 + j;
        float y = scan_y[(0 * DI_ + d) * L_ + l0 + l]
                + scan_y[(1 * DI_ + d) * L_ + l0 + l]
                + scan_y[(2 * DI_ + d) * L_ + l0 + l]
                + scan_y[(3 * DI_ + d) * L_ + l0 + l];
        yt[l][d] = y;
        psum += y;
    }
    red[g][l] = psum;
    __syncthreads();
    float mu = 0.f;
#pragma unroll
    for (int g2 = 0; g2 < 16; ++g2) mu += red[g2][l];
    mu *= (1.f / DI_);
    float pv = 0.f;
#pragma unroll
    for (int j = 0; j < 12; ++j) {
        float yc = yt[l][d0 + j] - mu;
        pv += yc * yc;
    }
    __syncthreads();
    red[g][l] = pv;
    __syncthreads();
    float var = 0.f;
#pragma unroll
    for (int g2 = 0; g2 < 16; ++g2) var += red[g2][l];
    var *= (1.f / DI_);
    float rstd = rsqrtf(var + 1e-5f);
#pragma unroll
    for (int j = 0; j < 12; ++j) {
        int d = d0 + j;
        float zv = xzT[(DI_ + d) * L_ + l0 + l];
        float yn = (yt[l][d] - mu) * rstd * onw[d] + onb[d];
        yt[l][d] = yn * sp_silu(zv);
    }
    __syncthreads();
    int c0 = g * 6;
    float acc[6] = {0.f, 0.f, 0.f, 0.f, 0.f, 0.f};
    for (int dd = 0; dd < DI_; dd += 4) {
        float4 yv = *(const float4*)&yt[l][dd];
#pragma unroll
        for (int j = 0; j < 6; ++j) {
            float4 wv = *(const float4*)&Wout[(c0 + j) * DI_ + dd];
            acc[j] += yv.x * wv.x + yv.y * wv.y + yv.z * wv.z + yv.w * wv.w;
        }
    }
    float ss = 0.f;
    float x2v[6];
#pragma unroll
    for (int j = 0; j < 6; ++j) {
        int c = c0 + j;
        float v = x[c * L_ + l0 + l] + acc[j];
        x2v[j] = v; ss += v * v;
        x2[c * L_ + l0 + l] = v;
    }
    __syncthreads();
    red[g][l] = ss;
    __syncthreads();
    float tot = 0.f;
#pragma unroll
    for (int g2 = 0; g2 < 16; ++g2) tot += red[g2][l];
    float r2 = rsqrtf(tot * (1.f / C96) + 1e-6f);
#pragma unroll
    for (int j = 0; j < 6; ++j) {
        int c = c0 + j;
        n2[c * L_ + l0 + l] = x2v[j] * r2 * w2[c] + b2[c];
    }
}

// K12: EDFFN pin GEMM, LDS-staged. grid (64, 8), 16 o/thread, clamp at 510.
__global__ __launch_bounds__(256) void k_pin2(const float* __restrict__ n2,
        const float* __restrict__ W, float* __restrict__ hf) {
    __shared__ float sx[C96][64];
    int l0 = blockIdx.x * 64;
    int t = threadIdx.x;
    for (int i = t; i < C96 * 64; i += 256) {
        int c = i >> 6, l = i & 63;
        sx[c][l] = n2[c * L_ + l0 + l];
    }
    __syncthreads();
    int l = t & 63, og = t >> 6;
    int o0 = blockIdx.y * 64 + og * 16;
    float acc[16];
#pragma unroll
    for (int j = 0; j < 16; ++j) acc[j] = 0.f;
    for (int c = 0; c < C96; ++c) {
        float v = sx[c][l];
#pragma unroll
        for (int j = 0; j < 16; ++j) {
            int oj = o0 + j; if (oj > 509) oj = 509;   // clamp keeps loads uniform
            acc[j] += v * W[oj * C96 + c];
        }
    }
#pragma unroll
    for (int j = 0; j < 16; ++j) {
        int o = o0 + j;
        if (o < 510) hf[o * L_ + l0 + l] = acc[j];
    }
}

// K13: depthwise 3x3 (no bias) on 510 channels + GELU(h1)*h2 gate.
__global__ void k_ffnconv(const float* __restrict__ hf, const float* __restrict__ w,
                          float* __restrict__ g) {
    int idx = blockIdx.x * 256 + threadIdx.x;
    if (idx >= HF_ * L_) return;
    int c = idx / L_, l = idx % L_;
    int h = l >> 6, wc = l & 63;
    float s1 = 0.f, s2 = 0.f;
#pragma unroll
    for (int di = -1; di <= 1; ++di)
#pragma unroll
        for (int dj = -1; dj <= 1; ++dj) {
            int hh = h + di, ww = wc + dj;
            if (hh >= 0 && hh < HW_ && ww >= 0 && ww < HW_) {
                int p = hh * HW_ + ww;
                int widx = (di + 1) * 3 + (dj + 1);
                s1 += hf[c * L_ + p] * w[c * 9 + widx];
                s2 += hf[(c + HF_) * L_ + p] * w[(c + HF_) * 9 + widx];
            }
        }
    float ge = 0.5f * s1 * (1.f + erff(s1 * 0.70710678118654752f));
    g[idx] = ge * s2;
}

// K14v3: pout GEMM + residual. grid (64, 4), 256 blocks. Stage FULL g tile
// [255][64] (65 KB LDS, 2 blocks/CU) once; 6 c/thread; W wave-uniform.
__global__ __launch_bounds__(256) void k_pout3(const float* __restrict__ g,
        const float* __restrict__ W, const float* __restrict__ x2,
        float* __restrict__ out) {
    __shared__ float sg[HF_][64];
    int l0 = blockIdx.x * 64;
    int t = threadIdx.x;
    for (int i = t; i < HF_ * 64; i += 256) {
        int c = i >> 6, ll = i & 63;
        sg[c][ll] = g[c * L_ + l0 + ll];
    }
    __syncthreads();
    int l = t & 63, og = t >> 6;
    int c0 = blockIdx.y * 24 + og * 6;
    float acc[6] = {0.f, 0.f, 0.f, 0.f, 0.f, 0.f};
    for (int c = 0; c < HF_; ++c) {
        float v = sg[c][l];
#pragma unroll
        for (int j = 0; j < 6; ++j) acc[j] += v * W[(c0 + j) * HF_ + c];
    }
#pragma unroll
    for (int j = 0; j < 6; ++j) {
        int c = c0 + j;
        out[c * L_ + l0 + l] = x2[c * L_ + l0 + l] + acc[j];
    }
}

extern "C" void kernel_launch(void* const* d_in, const int* in_sizes, int n_in,
                              void* d_out, int out_size, void* d_ws, size_t ws_size,
                              hipStream_t stream) {
    const float* x         = (const float*)d_in[0];
    const float* norm1_w   = (const float*)d_in[1];
    const float* norm1_b   = (const float*)d_in[2];
    const float* in_proj_w = (const float*)d_in[3];
    const float* conv2d_w  = (const float*)d_in[4];
    const float* conv2d_b  = (const float*)d_in[5];
    const float* x_proj_w  = (const float*)d_in[6];
    const float* dt_projs_w= (const float*)d_in[7];
    const float* dt_projs_b= (const float*)d_in[8];
    const float* A_logs    = (const float*)d_in[9];
    const float* Ds        = (const float*)d_in[10];
    const float* out_norm_w= (const float*)d_in[11];
    const float* out_norm_b= (const float*)d_in[12];
    const float* out_proj_w= (const float*)d_in[13];
    const float* norm2_w   = (const float*)d_in[14];
    const float* norm2_b   = (const float*)d_in[15];
    const float* pin_w     = (const float*)d_in[16];
    const float* dw_w      = (const float*)d_in[17];
    const float* pout_w    = (const float*)d_in[18];

    float* ws = (float*)d_ws;
    float* n1     = ws; ws += C96 * L_;          // reused as dtsb after inproj
    float* xzT    = ws; ws += 2 * DI_ * L_;
    float* xconv  = ws; ws += DI_ * L_;
    float* xs     = ws; ws += Kk * DI_ * L_;     // reused as hf after scan
    float* delta  = ws; ws += Kk * DI_ * L_;     // reused as gbuf after scan
    float* BsT    = ws; ws += Kk * L_ * Nn;
    float* CsT    = ws; ws += Kk * L_ * Nn;
    float* scan_y = ws; ws += Kk * DI_ * L_;
    float* x2     = ws; ws += C96 * L_;
    float* n2     = ws; ws += C96 * L_;
    float* dtsb   = n1;
    float* hf     = xs;
    float* gbuf   = delta;

    k_rmsln1<<<256, 256, 0, stream>>>(x, norm1_w, norm1_b, n1);
    k_inproj2<<<dim3(64, 6), 256, 0, stream>>>(n1, in_proj_w, xzT);
    k_conv192<<<3072, 256, 0, stream>>>(xzT, conv2d_w, conv2d_b, xconv);
    k_build_xs<<<12288, 256, 0, stream>>>(xconv, xs);
    k_xdbl2<<<dim3(64, 4), 256, 0, stream>>>(xs, x_proj_w, dtsb, BsT, CsT);
    k_delta<<<12288, 256, 0, stream>>>(dtsb, dt_projs_w, dt_projs_b, delta);
    k_scan<<<768, 256, 0, stream>>>(delta, xs, BsT, CsT, A_logs, Ds, scan_y);
    k_combine3<<<256, 256, 0, stream>>>(scan_y, out_norm_w, out_norm_b, xzT,
                                        out_proj_w, x, norm2_w, norm2_b, x2, n2);
    k_pin2<<<dim3(64, 8), 256, 0, stream>>>(n2, pin_w, hf);
    k_ffnconv<<<4080, 256, 0, stream>>>(hf, dw_w, gbuf);
    k_pout3<<<dim3(64, 4), 256, 0, stream>>>(gbuf, pout_w, x2, (float*)d_out);
}

// Round 9
// 203.479 us; speedup vs baseline: 1.5877x; 1.3300x over previous
//
#include <hip/hip_runtime.h>
#include <hip/hip_bf16.h>
#include <math.h>

#define L_    4096
#define C96   96
#define DI_   192
#define Nn    16
#define Rr    6
#define Kk    4
#define HW_   64
#define HF_   255

__device__ __forceinline__ float sp_softplus(float s) {
    return fmaxf(s, 0.f) + log1pf(expf(-fabsf(s)));
}
__device__ __forceinline__ float sp_silu(float s) {
    return s / (1.f + expf(-s));
}
// quad-perm DPP shuffles (full-rate VALU, lanes within quad)
__device__ __forceinline__ float qxor1(float x) {
    return __int_as_float(__builtin_amdgcn_update_dpp(0, __float_as_int(x),
                                                      0xB1, 0xF, 0xF, true));
}
__device__ __forceinline__ float qxor2(float x) {
    return __int_as_float(__builtin_amdgcn_update_dpp(0, __float_as_int(x),
                                                      0x4E, 0xF, 0xF, true));
}

// K1: RMS-LN, l-tile=16, 16 groups x 6 channels. grid=256.
__global__ __launch_bounds__(256) void k_rmsln1(const float* __restrict__ x,
        const float* __restrict__ w, const float* __restrict__ b,
        float* __restrict__ n1) {
    __shared__ float red[16][16];
    int l0 = blockIdx.x * 16;
    int t = threadIdx.x;
    int l = t & 15, g = t >> 4;
    float xv[6];
    float ss = 0.f;
#pragma unroll
    for (int j = 0; j < 6; ++j) {
        int c = g * 6 + j;
        xv[j] = x[c * L_ + l0 + l];
        ss += xv[j] * xv[j];
    }
    red[g][l] = ss;
    __syncthreads();
    float tot = 0.f;
#pragma unroll
    for (int g2 = 0; g2 < 16; ++g2) tot += red[g2][l];
    float r = rsqrtf(tot * (1.f / C96) + 1e-6f);
#pragma unroll
    for (int j = 0; j < 6; ++j) {
        int c = g * 6 + j;
        n1[c * L_ + l0 + l] = xv[j] * r * w[c] + b[c];
    }
}

// K2v3/K12v3: generic K=96 FC microkernel. grid (64, O_pad/64), block 256.
// Dual LDS operands: act tile sx[96][64] + W tile wl[64][100] (pad 100:
// b128 staging writes conflict-free; inner-loop row reads 2-way = free).
// Thread = 4l x 4o register tile; per c: 1 b128 + 4 b32 + 16 indep FMA.
__global__ __launch_bounds__(256) void k_fc96(const float* __restrict__ act,
        const float* __restrict__ W, float* __restrict__ out, int Orows) {
    __shared__ float sx[C96][64];
    __shared__ float wl[64][100];
    int l0 = blockIdx.x * 64;
    int o0 = blockIdx.y * 64;
    int t = threadIdx.x;
    for (int i = t; i < C96 * 64; i += 256) {
        int c = i >> 6, l = i & 63;
        sx[c][l] = act[c * L_ + l0 + l];
    }
    for (int i = t; i < 64 * 24; i += 256) {
        int o = i / 24, cq = (i % 24) * 4;
        int orow = o0 + o; if (orow > Orows - 1) orow = Orows - 1;
        float4 wv = *(const float4*)&W[orow * C96 + cq];
        *(float4*)&wl[o][cq] = wv;
    }
    __syncthreads();
    int lq = t & 15, oq = t >> 4;
    float4 acc[4];
#pragma unroll
    for (int j = 0; j < 4; ++j) acc[j] = make_float4(0.f, 0.f, 0.f, 0.f);
#pragma unroll 4
    for (int c = 0; c < C96; ++c) {
        float4 a = *(const float4*)&sx[c][lq * 4];
#pragma unroll
        for (int j = 0; j < 4; ++j) {
            float wv = wl[oq * 4 + j][c];
            acc[j].x += wv * a.x; acc[j].y += wv * a.y;
            acc[j].z += wv * a.z; acc[j].w += wv * a.w;
        }
    }
#pragma unroll
    for (int j = 0; j < 4; ++j) {
        int o = o0 + oq * 4 + j;
        if (o < Orows)
            *(float4*)&out[o * L_ + l0 + lq * 4] = acc[j];
    }
}

// K3: depthwise 3x3 conv (SAME) + bias + SiLU on xc (192, 64, 64).
__global__ void k_conv192(const float* __restrict__ xc, const float* __restrict__ w,
                          const float* __restrict__ b, float* __restrict__ out) {
    int idx = blockIdx.x * 256 + threadIdx.x;
    if (idx >= DI_ * L_) return;
    int c = idx / L_, l = idx % L_;
    int h = l >> 6, wc = l & 63;
    float s = b[c];
#pragma unroll
    for (int di = -1; di <= 1; ++di)
#pragma unroll
        for (int dj = -1; dj <= 1; ++dj) {
            int hh = h + di, ww = wc + dj;
            if (hh >= 0 && hh < HW_ && ww >= 0 && ww < HW_)
                s += xc[c * L_ + hh * HW_ + ww] * w[c * 9 + (di + 1) * 3 + (dj + 1)];
        }
    out[idx] = sp_silu(s);
}

// K4: materialize 4 direction views xs[(k*DI+d)*L + l]
__global__ void k_build_xs(const float* __restrict__ xconv, float* __restrict__ xs) {
    int idx = blockIdx.x * 256 + threadIdx.x;
    if (idx >= Kk * DI_ * L_) return;
    int l = idx % L_; int kd = idx / L_; int d = kd % DI_; int k = kd / DI_;
    int ll = (k & 2) ? (L_ - 1 - l) : l;
    int pos = (k & 1) ? ((ll & 63) * 64 + (ll >> 6)) : ll;
    xs[idx] = xconv[d * L_ + pos];
}

// K5: x_proj GEMM fused with B/C transpose. Block=256: one k, 64-wide l tile.
__global__ __launch_bounds__(256) void k_xdbl2(const float* __restrict__ xs,
        const float* __restrict__ Wxp, float* __restrict__ dts,
        float* __restrict__ BsT, float* __restrict__ CsT) {
    __shared__ float sx[DI_][64];
    int k = blockIdx.y;
    int l0 = blockIdx.x * 64;
    int t = threadIdx.x;
    const float* src = xs + (k * DI_) * L_ + l0;
    for (int i = t; i < DI_ * 64; i += 256) {
        int d = i >> 6, l = i & 63;
        sx[d][l] = src[d * L_ + l];
    }
    __syncthreads();
    int l = t & 63, cg = t >> 6;
    int c0 = cg * 10;
    int cnt = (cg == 3) ? 8 : 10;
    float acc[10] = {0.f, 0.f, 0.f, 0.f, 0.f, 0.f, 0.f, 0.f, 0.f, 0.f};
    const float* Wk = Wxp + k * 38 * DI_;
    for (int d = 0; d < DI_; ++d) {
        float v = sx[d][l];
#pragma unroll
        for (int j = 0; j < 10; ++j) {
            int cj = c0 + j; if (cj > 37) cj = 37;
            acc[j] += v * Wk[cj * DI_ + d];
        }
    }
    int gl = l0 + l;
#pragma unroll
    for (int j = 0; j < 10; ++j) {
        if (j < cnt) {
            int c = c0 + j;
            float v = acc[j];
            if (c < Rr)           dts[(k * Rr + c) * L_ + gl] = v;
            else if (c < Rr + Nn) BsT[(k * L_ + gl) * Nn + (c - Rr)] = v;
            else                  CsT[(k * L_ + gl) * Nn + (c - Rr - Nn)] = v;
        }
    }
}

// K6: delta[kd, l] = softplus(sum_r dts[k,r,l] * dtw[kd,r] + dtb[kd])
__global__ void k_delta(const float* __restrict__ dts, const float* __restrict__ dtw,
                        const float* __restrict__ dtb, float* __restrict__ delta) {
    int idx = blockIdx.x * 256 + threadIdx.x;
    if (idx >= Kk * DI_ * L_) return;
    int l = idx % L_; int kd = idx / L_; int k = kd / DI_;
    float s = dtb[kd];
#pragma unroll
    for (int r = 0; r < Rr; ++r)
        s += dts[(k * Rr + r) * L_ + l] * dtw[kd * Rr + r];
    delta[idx] = sp_softplus(s);
}

// K8: FUSED selective scan. One block per kd (grid=768, 256 thr).
__global__ __launch_bounds__(256) void k_scan(const float* __restrict__ delta,
        const float* __restrict__ xs, const float* __restrict__ BsT,
        const float* __restrict__ CsT, const float* __restrict__ A_logs,
        const float* __restrict__ Ds, float* __restrict__ scan_y) {
    __shared__ float dl_s[64 * 65];
    __shared__ float u_s[64 * 65];
    __shared__ float ys[64 * 65];
    __shared__ float Pl[64][16];
    __shared__ float Sl[64][16];
    int kd = blockIdx.x; int k = kd / DI_;
    int t = threadIdx.x;
    {
        const float4* dg = (const float4*)(delta + kd * L_);
        const float4* ug = (const float4*)(xs + kd * L_);
        for (int s = t; s < 1024; s += 256) {
            float4 dv = dg[s], uv = ug[s];
            int o = (s >> 4) * 65 + ((s << 2) & 63);
            dl_s[o] = dv.x; dl_s[o + 1] = dv.y; dl_s[o + 2] = dv.z; dl_s[o + 3] = dv.w;
            u_s[o] = uv.x;  u_s[o + 1] = uv.y;  u_s[o + 2] = uv.z;  u_s[o + 3] = uv.w;
        }
    }
    int g = t >> 2, j = t & 3;
    float4 Al = *(const float4*)&A_logs[kd * Nn + 4 * j];
    float A0 = -__expf(Al.x), A1 = -__expf(Al.y), A2 = -__expf(Al.z), A3 = -__expf(Al.w);
    __syncthreads();
    int lo = g * 65;
    const float4* Bv = (const float4*)&BsT[(k * L_ + g * 64) * Nn + 4 * j];
    const float4* Cv = (const float4*)&CsT[(k * L_ + g * 64) * Nn + 4 * j];
    float h0 = 0.f, h1 = 0.f, h2 = 0.f, h3 = 0.f;
    float p0 = 1.f, p1 = 1.f, p2 = 1.f, p3 = 1.f;
    for (int i = 0; i < 64; ++i) {
        float dl = dl_s[lo + i], ul = u_s[lo + i];
        float4 bv = Bv[i * 4];
        float du = dl * ul;
        float e0 = __expf(dl * A0), e1 = __expf(dl * A1);
        float e2 = __expf(dl * A2), e3 = __expf(dl * A3);
        h0 = e0 * h0 + du * bv.x; h1 = e1 * h1 + du * bv.y;
        h2 = e2 * h2 + du * bv.z; h3 = e3 * h3 + du * bv.w;
        p0 *= e0; p1 *= e1; p2 *= e2; p3 *= e3;
    }
    *(float4*)&Pl[g][4 * j] = make_float4(p0, p1, p2, p3);
    *(float4*)&Sl[g][4 * j] = make_float4(h0, h1, h2, h3);
    __syncthreads();
    for (int s = 1; s < 64; s <<= 1) {
        float4 pp, sp;
        bool act = (g >= s);
        if (act) {
            pp = *(float4*)&Pl[g - s][4 * j];
            sp = *(float4*)&Sl[g - s][4 * j];
        }
        __syncthreads();
        if (act) {
            float4 pc = *(float4*)&Pl[g][4 * j];
            float4 sc = *(float4*)&Sl[g][4 * j];
            *(float4*)&Pl[g][4 * j] =
                make_float4(pp.x * pc.x, pp.y * pc.y, pp.z * pc.z, pp.w * pc.w);
            *(float4*)&Sl[g][4 * j] =
                make_float4(pc.x * sp.x + sc.x, pc.y * sp.y + sc.y,
                            pc.z * sp.z + sc.z, pc.w * sp.w + sc.w);
        }
        __syncthreads();
    }
    float4 hv = make_float4(0.f, 0.f, 0.f, 0.f);
    if (g > 0) hv = *(const float4*)&Sl[g - 1][4 * j];
    float Dp = Ds[kd];
    h0 = hv.x; h1 = hv.y; h2 = hv.z; h3 = hv.w;
    for (int i = 0; i < 64; ++i) {
        float dl = dl_s[lo + i], ul = u_s[lo + i];
        float4 bv = Bv[i * 4];
        float4 cv = Cv[i * 4];
        float du = dl * ul;
        float e0 = __expf(dl * A0), e1 = __expf(dl * A1);
        float e2 = __expf(dl * A2), e3 = __expf(dl * A3);
        h0 = e0 * h0 + du * bv.x; h1 = e1 * h1 + du * bv.y;
        h2 = e2 * h2 + du * bv.z; h3 = e3 * h3 + du * bv.w;
        float ps = h0 * cv.x + h1 * cv.y + h2 * cv.z + h3 * cv.w;
        ps += qxor1(ps);
        ps += qxor2(ps);
        if (j == 0) ys[lo + i] = ps + Dp * ul;
    }
    __syncthreads();
    float* yout = scan_y + kd * L_;
    for (int p = t; p < L_; p += 256) {
        int ll = (k & 1) ? (((p & 63) << 6) | (p >> 6)) : p;
        int sl = (k & 2) ? (L_ - 1 - ll) : ll;
        yout[p] = ys[sl + (sl >> 6)];
    }
}

// K11: l-tile=16, grid=256 blocks, 256 threads = 16 groups x 16 lanes.
__global__ __launch_bounds__(256) void k_combine3(
        const float* __restrict__ scan_y, const float* __restrict__ onw,
        const float* __restrict__ onb, const float* __restrict__ xzT,
        const float* __restrict__ Wout, const float* __restrict__ x,
        const float* __restrict__ w2, const float* __restrict__ b2,
        float* __restrict__ x2, float* __restrict__ n2) {
    __shared__ float yt[16][196];
    __shared__ float red[16][16];
    int l0 = blockIdx.x * 16;
    int t = threadIdx.x;
    int l = t & 15, g = t >> 4;
    int d0 = g * 12;
    float psum = 0.f;
#pragma unroll
    for (int j = 0; j < 12; ++j) {
        int d = d0 + j;
        float y = scan_y[(0 * DI_ + d) * L_ + l0 + l]
                + scan_y[(1 * DI_ + d) * L_ + l0 + l]
                + scan_y[(2 * DI_ + d) * L_ + l0 + l]
                + scan_y[(3 * DI_ + d) * L_ + l0 + l];
        yt[l][d] = y;
        psum += y;
    }
    red[g][l] = psum;
    __syncthreads();
    float mu = 0.f;
#pragma unroll
    for (int g2 = 0; g2 < 16; ++g2) mu += red[g2][l];
    mu *= (1.f / DI_);
    float pv = 0.f;
#pragma unroll
    for (int j = 0; j < 12; ++j) {
        float yc = yt[l][d0 + j] - mu;
        pv += yc * yc;
    }
    __syncthreads();
    red[g][l] = pv;
    __syncthreads();
    float var = 0.f;
#pragma unroll
    for (int g2 = 0; g2 < 16; ++g2) var += red[g2][l];
    var *= (1.f / DI_);
    float rstd = rsqrtf(var + 1e-5f);
#pragma unroll
    for (int j = 0; j < 12; ++j) {
        int d = d0 + j;
        float zv = xzT[(DI_ + d) * L_ + l0 + l];
        float yn = (yt[l][d] - mu) * rstd * onw[d] + onb[d];
        yt[l][d] = yn * sp_silu(zv);
    }
    __syncthreads();
    int c0 = g * 6;
    float acc[6] = {0.f, 0.f, 0.f, 0.f, 0.f, 0.f};
    for (int dd = 0; dd < DI_; dd += 4) {
        float4 yv = *(const float4*)&yt[l][dd];
#pragma unroll
        for (int j = 0; j < 6; ++j) {
            float4 wv = *(const float4*)&Wout[(c0 + j) * DI_ + dd];
            acc[j] += yv.x * wv.x + yv.y * wv.y + yv.z * wv.z + yv.w * wv.w;
        }
    }
    float ss = 0.f;
    float x2v[6];
#pragma unroll
    for (int j = 0; j < 6; ++j) {
        int c = c0 + j;
        float v = x[c * L_ + l0 + l] + acc[j];
        x2v[j] = v; ss += v * v;
        x2[c * L_ + l0 + l] = v;
    }
    __syncthreads();
    red[g][l] = ss;
    __syncthreads();
    float tot = 0.f;
#pragma unroll
    for (int g2 = 0; g2 < 16; ++g2) tot += red[g2][l];
    float r2 = rsqrtf(tot * (1.f / C96) + 1e-6f);
#pragma unroll
    for (int j = 0; j < 6; ++j) {
        int c = c0 + j;
        n2[c * L_ + l0 + l] = x2v[j] * r2 * w2[c] + b2[c];
    }
}

// K13: depthwise 3x3 (no bias) on 510 channels + GELU(h1)*h2 gate.
__global__ void k_ffnconv(const float* __restrict__ hf, const float* __restrict__ w,
                          float* __restrict__ g) {
    int idx = blockIdx.x * 256 + threadIdx.x;
    if (idx >= HF_ * L_) return;
    int c = idx / L_, l = idx % L_;
    int h = l >> 6, wc = l & 63;
    float s1 = 0.f, s2 = 0.f;
#pragma unroll
    for (int di = -1; di <= 1; ++di)
#pragma unroll
        for (int dj = -1; dj <= 1; ++dj) {
            int hh = h + di, ww = wc + dj;
            if (hh >= 0 && hh < HW_ && ww >= 0 && ww < HW_) {
                int p = hh * HW_ + ww;
                int widx = (di + 1) * 3 + (dj + 1);
                s1 += hf[c * L_ + p] * w[c * 9 + widx];
                s2 += hf[(c + HF_) * L_ + p] * w[(c + HF_) * 9 + widx];
            }
        }
    float ge = 0.5f * s1 * (1.f + erff(s1 * 0.70710678118654752f));
    g[idx] = ge * s2;
}

// K14: pout GEMM + residual. grid (64, 4), 256 blocks. Stage FULL g tile
// [255][64] (65 KB LDS) once; 6 c/thread; W wave-uniform.
__global__ __launch_bounds__(256) void k_pout3(const float* __restrict__ g,
        const float* __restrict__ W, const float* __restrict__ x2,
        float* __restrict__ out) {
    __shared__ float sg[HF_][64];
    int l0 = blockIdx.x * 64;
    int t = threadIdx.x;
    for (int i = t; i < HF_ * 64; i += 256) {
        int c = i >> 6, ll = i & 63;
        sg[c][ll] = g[c * L_ + l0 + ll];
    }
    __syncthreads();
    int l = t & 63, og = t >> 6;
    int c0 = blockIdx.y * 24 + og * 6;
    float acc[6] = {0.f, 0.f, 0.f, 0.f, 0.f, 0.f};
    for (int c = 0; c < HF_; ++c) {
        float v = sg[c][l];
#pragma unroll
        for (int j = 0; j < 6; ++j) acc[j] += v * W[(c0 + j) * HF_ + c];
    }
#pragma unroll
    for (int j = 0; j < 6; ++j) {
        int c = c0 + j;
        out[c * L_ + l0 + l] = x2[c * L_ + l0 + l] + acc[j];
    }
}

extern "C" void kernel_launch(void* const* d_in, const int* in_sizes, int n_in,
                              void* d_out, int out_size, void* d_ws, size_t ws_size,
                              hipStream_t stream) {
    const float* x         = (const float*)d_in[0];
    const float* norm1_w   = (const float*)d_in[1];
    const float* norm1_b   = (const float*)d_in[2];
    const float* in_proj_w = (const float*)d_in[3];
    const float* conv2d_w  = (const float*)d_in[4];
    const float* conv2d_b  = (const float*)d_in[5];
    const float* x_proj_w  = (const float*)d_in[6];
    const float* dt_projs_w= (const float*)d_in[7];
    const float* dt_projs_b= (const float*)d_in[8];
    const float* A_logs    = (const float*)d_in[9];
    const float* Ds        = (const float*)d_in[10];
    const float* out_norm_w= (const float*)d_in[11];
    const float* out_norm_b= (const float*)d_in[12];
    const float* out_proj_w= (const float*)d_in[13];
    const float* norm2_w   = (const float*)d_in[14];
    const float* norm2_b   = (const float*)d_in[15];
    const float* pin_w     = (const float*)d_in[16];
    const float* dw_w      = (const float*)d_in[17];
    const float* pout_w    = (const float*)d_in[18];

    float* ws = (float*)d_ws;
    float* n1     = ws; ws += C96 * L_;          // reused as dtsb after inproj
    float* xzT    = ws; ws += 2 * DI_ * L_;
    float* xconv  = ws; ws += DI_ * L_;
    float* xs     = ws; ws += Kk * DI_ * L_;     // reused as hf after scan
    float* delta  = ws; ws += Kk * DI_ * L_;     // reused as gbuf after scan
    float* BsT    = ws; ws += Kk * L_ * Nn;
    float* CsT    = ws; ws += Kk * L_ * Nn;
    float* scan_y = ws; ws += Kk * DI_ * L_;
    float* x2     = ws; ws += C96 * L_;
    float* n2     = ws; ws += C96 * L_;
    float* dtsb   = n1;
    float* hf     = xs;
    float* gbuf   = delta;

    k_rmsln1<<<256, 256, 0, stream>>>(x, norm1_w, norm1_b, n1);
    k_fc96<<<dim3(64, 6), 256, 0, stream>>>(n1, in_proj_w, xzT, 2 * DI_);
    k_conv192<<<3072, 256, 0, stream>>>(xzT, conv2d_w, conv2d_b, xconv);
    k_build_xs<<<12288, 256, 0, stream>>>(xconv, xs);
    k_xdbl2<<<dim3(64, 4), 256, 0, stream>>>(xs, x_proj_w, dtsb, BsT, CsT);
    k_delta<<<12288, 256, 0, stream>>>(dtsb, dt_projs_w, dt_projs_b, delta);
    k_scan<<<768, 256, 0, stream>>>(delta, xs, BsT, CsT, A_logs, Ds, scan_y);
    k_combine3<<<256, 256, 0, stream>>>(scan_y, out_norm_w, out_norm_b, xzT,
                                        out_proj_w, x, norm2_w, norm2_b, x2, n2);
    k_fc96<<<dim3(64, 8), 256, 0, stream>>>(n2, pin_w, hf, 2 * HF_);
    k_ffnconv<<<4080, 256, 0, stream>>>(hf, dw_w, gbuf);
    k_pout3<<<dim3(64, 4), 256, 0, stream>>>(gbuf, pout_w, x2, (float*)d_out);
}

// Round 10
// 175.206 us; speedup vs baseline: 1.8439x; 1.1614x over previous
//
#include <hip/hip_runtime.h>
#include <hip/hip_bf16.h>
#include <math.h>

#define L_    4096
#define C96   96
#define DI_   192
#define Nn    16
#define Rr    6
#define Kk    4
#define HW_   64
#define HF_   255
#define SCH   32
#define SNC   128

__device__ __forceinline__ float sp_softplus(float s) {
    return fmaxf(s, 0.f) + log1pf(expf(-fabsf(s)));
}
__device__ __forceinline__ float sp_silu(float s) {
    return s / (1.f + expf(-s));
}
// quad-perm DPP shuffles (full-rate VALU, lanes within quad)
__device__ __forceinline__ float qxor1(float x) {
    return __int_as_float(__builtin_amdgcn_update_dpp(0, __float_as_int(x),
                                                      0xB1, 0xF, 0xF, true));
}
__device__ __forceinline__ float qxor2(float x) {
    return __int_as_float(__builtin_amdgcn_update_dpp(0, __float_as_int(x),
                                                      0x4E, 0xF, 0xF, true));
}

// K1: RMS-LN, l-tile=16, 16 groups x 6 channels. grid=256.
__global__ __launch_bounds__(256) void k_rmsln1(const float* __restrict__ x,
        const float* __restrict__ w, const float* __restrict__ b,
        float* __restrict__ n1) {
    __shared__ float red[16][16];
    int l0 = blockIdx.x * 16;
    int t = threadIdx.x;
    int l = t & 15, g = t >> 4;
    float xv[6];
    float ss = 0.f;
#pragma unroll
    for (int j = 0; j < 6; ++j) {
        int c = g * 6 + j;
        xv[j] = x[c * L_ + l0 + l];
        ss += xv[j] * xv[j];
    }
    red[g][l] = ss;
    __syncthreads();
    float tot = 0.f;
#pragma unroll
    for (int g2 = 0; g2 < 16; ++g2) tot += red[g2][l];
    float r = rsqrtf(tot * (1.f / C96) + 1e-6f);
#pragma unroll
    for (int j = 0; j < 6; ++j) {
        int c = g * 6 + j;
        n1[c * L_ + l0 + l] = xv[j] * r * w[c] + b[c];
    }
}

// K2/K12: generic K=96 FC microkernel. Dual LDS operands; 4l x 4o per thread.
__global__ __launch_bounds__(256) void k_fc96(const float* __restrict__ act,
        const float* __restrict__ W, float* __restrict__ out, int Orows) {
    __shared__ float sx[C96][64];
    __shared__ float wl[64][100];
    int l0 = blockIdx.x * 64;
    int o0 = blockIdx.y * 64;
    int t = threadIdx.x;
    for (int i = t; i < C96 * 64; i += 256) {
        int c = i >> 6, l = i & 63;
        sx[c][l] = act[c * L_ + l0 + l];
    }
    for (int i = t; i < 64 * 24; i += 256) {
        int o = i / 24, cq = (i % 24) * 4;
        int orow = o0 + o; if (orow > Orows - 1) orow = Orows - 1;
        float4 wv = *(const float4*)&W[orow * C96 + cq];
        *(float4*)&wl[o][cq] = wv;
    }
    __syncthreads();
    int lq = t & 15, oq = t >> 4;
    float4 acc[4];
#pragma unroll
    for (int j = 0; j < 4; ++j) acc[j] = make_float4(0.f, 0.f, 0.f, 0.f);
#pragma unroll 4
    for (int c = 0; c < C96; ++c) {
        float4 a = *(const float4*)&sx[c][lq * 4];
#pragma unroll
        for (int j = 0; j < 4; ++j) {
            float wv = wl[oq * 4 + j][c];
            acc[j].x += wv * a.x; acc[j].y += wv * a.y;
            acc[j].z += wv * a.z; acc[j].w += wv * a.w;
        }
    }
#pragma unroll
    for (int j = 0; j < 4; ++j) {
        int o = o0 + oq * 4 + j;
        if (o < Orows)
            *(float4*)&out[o * L_ + l0 + lq * 4] = acc[j];
    }
}

// K3: depthwise 3x3 conv (SAME) + bias + SiLU on xc (192, 64, 64).
__global__ void k_conv192(const float* __restrict__ xc, const float* __restrict__ w,
                          const float* __restrict__ b, float* __restrict__ out) {
    int idx = blockIdx.x * 256 + threadIdx.x;
    if (idx >= DI_ * L_) return;
    int c = idx / L_, l = idx % L_;
    int h = l >> 6, wc = l & 63;
    float s = b[c];
#pragma unroll
    for (int di = -1; di <= 1; ++di)
#pragma unroll
        for (int dj = -1; dj <= 1; ++dj) {
            int hh = h + di, ww = wc + dj;
            if (hh >= 0 && hh < HW_ && ww >= 0 && ww < HW_)
                s += xc[c * L_ + hh * HW_ + ww] * w[c * 9 + (di + 1) * 3 + (dj + 1)];
        }
    out[idx] = sp_silu(s);
}

// K4: materialize 4 direction views xs[(k*DI+d)*L + l]
__global__ void k_build_xs(const float* __restrict__ xconv, float* __restrict__ xs) {
    int idx = blockIdx.x * 256 + threadIdx.x;
    if (idx >= Kk * DI_ * L_) return;
    int l = idx % L_; int kd = idx / L_; int d = kd % DI_; int k = kd / DI_;
    int ll = (k & 2) ? (L_ - 1 - l) : l;
    int pos = (k & 1) ? ((ll & 63) * 64 + (ll >> 6)) : ll;
    xs[idx] = xconv[d * L_ + pos];
}

// K5: x_proj GEMM fused with B/C transpose. Block=256: one k, 64-wide l tile.
__global__ __launch_bounds__(256) void k_xdbl2(const float* __restrict__ xs,
        const float* __restrict__ Wxp, float* __restrict__ dts,
        float* __restrict__ BsT, float* __restrict__ CsT) {
    __shared__ float sx[DI_][64];
    int k = blockIdx.y;
    int l0 = blockIdx.x * 64;
    int t = threadIdx.x;
    const float* src = xs + (k * DI_) * L_ + l0;
    for (int i = t; i < DI_ * 64; i += 256) {
        int d = i >> 6, l = i & 63;
        sx[d][l] = src[d * L_ + l];
    }
    __syncthreads();
    int l = t & 63, cg = t >> 6;
    int c0 = cg * 10;
    int cnt = (cg == 3) ? 8 : 10;
    float acc[10] = {0.f, 0.f, 0.f, 0.f, 0.f, 0.f, 0.f, 0.f, 0.f, 0.f};
    const float* Wk = Wxp + k * 38 * DI_;
    for (int d = 0; d < DI_; ++d) {
        float v = sx[d][l];
#pragma unroll
        for (int j = 0; j < 10; ++j) {
            int cj = c0 + j; if (cj > 37) cj = 37;
            acc[j] += v * Wk[cj * DI_ + d];
        }
    }
    int gl = l0 + l;
#pragma unroll
    for (int j = 0; j < 10; ++j) {
        if (j < cnt) {
            int c = c0 + j;
            float v = acc[j];
            if (c < Rr)           dts[(k * Rr + c) * L_ + gl] = v;
            else if (c < Rr + Nn) BsT[(k * L_ + gl) * Nn + (c - Rr)] = v;
            else                  CsT[(k * L_ + gl) * Nn + (c - Rr - Nn)] = v;
        }
    }
}

// K8v4: FUSED selective scan, CH=32, 512 threads, delta fused at staging.
// One block per kd. LDS 49.7 KB -> 3 blocks/CU. u_s doubles as ys.
__global__ __launch_bounds__(512) void k_scan(const float* __restrict__ dts,
        const float* __restrict__ dtw, const float* __restrict__ dtb,
        const float* __restrict__ xs, const float* __restrict__ BsT,
        const float* __restrict__ CsT, const float* __restrict__ A_logs,
        const float* __restrict__ Ds, float* __restrict__ scan_y) {
    __shared__ float dl_s[64 * 65];
    __shared__ float u_s[64 * 65];     // phase C overwrites with y
    __shared__ float Pl[SNC][16];
    __shared__ float Sl[SNC][16];
    int kd = blockIdx.x; int k = kd / DI_;
    int t = threadIdx.x;
    // staging: u row + delta computed inline from 6 dts rows
    {
        const float4* ug = (const float4*)(xs + kd * L_);
        const float4* r0 = (const float4*)(dts + (k * Rr + 0) * L_);
        const float4* r1 = (const float4*)(dts + (k * Rr + 1) * L_);
        const float4* r2 = (const float4*)(dts + (k * Rr + 2) * L_);
        const float4* r3 = (const float4*)(dts + (k * Rr + 3) * L_);
        const float4* r4 = (const float4*)(dts + (k * Rr + 4) * L_);
        const float4* r5 = (const float4*)(dts + (k * Rr + 5) * L_);
        float w0 = dtw[kd * Rr + 0], w1 = dtw[kd * Rr + 1], w2 = dtw[kd * Rr + 2];
        float w3 = dtw[kd * Rr + 3], w4 = dtw[kd * Rr + 4], w5 = dtw[kd * Rr + 5];
        float bb = dtb[kd];
        for (int s = t; s < 1024; s += 512) {
            float4 uv = ug[s];
            float4 v0 = r0[s], v1 = r1[s], v2 = r2[s];
            float4 v3 = r3[s], v4 = r4[s], v5 = r5[s];
            float4 dv;
            dv.x = sp_softplus(bb + w0 * v0.x + w1 * v1.x + w2 * v2.x
                                  + w3 * v3.x + w4 * v4.x + w5 * v5.x);
            dv.y = sp_softplus(bb + w0 * v0.y + w1 * v1.y + w2 * v2.y
                                  + w3 * v3.y + w4 * v4.y + w5 * v5.y);
            dv.z = sp_softplus(bb + w0 * v0.z + w1 * v1.z + w2 * v2.z
                                  + w3 * v3.z + w4 * v4.z + w5 * v5.z);
            dv.w = sp_softplus(bb + w0 * v0.w + w1 * v1.w + w2 * v2.w
                                  + w3 * v3.w + w4 * v4.w + w5 * v5.w);
            int o = (s >> 4) * 65 + ((s << 2) & 63);
            dl_s[o] = dv.x; dl_s[o + 1] = dv.y; dl_s[o + 2] = dv.z; dl_s[o + 3] = dv.w;
            u_s[o] = uv.x;  u_s[o + 1] = uv.y;  u_s[o + 2] = uv.z;  u_s[o + 3] = uv.w;
        }
    }
    int g = t >> 2, j = t & 3;
    float4 Al = *(const float4*)&A_logs[kd * Nn + 4 * j];
    float A0 = -__expf(Al.x), A1 = -__expf(Al.y), A2 = -__expf(Al.z), A3 = -__expf(Al.w);
    __syncthreads();
    int start = g * SCH;
    int lo = start + (start >> 6);
    const float4* Bv = (const float4*)&BsT[(k * L_ + start) * Nn + 4 * j];
    const float4* Cv = (const float4*)&CsT[(k * L_ + start) * Nn + 4 * j];
    // phase A: chunk-local scan, h0 = 0
    float h0 = 0.f, h1 = 0.f, h2 = 0.f, h3 = 0.f;
    float p0 = 1.f, p1 = 1.f, p2 = 1.f, p3 = 1.f;
    for (int i = 0; i < SCH; ++i) {
        float dl = dl_s[lo + i], ul = u_s[lo + i];
        float4 bv = Bv[i * 4];
        float du = dl * ul;
        float e0 = __expf(dl * A0), e1 = __expf(dl * A1);
        float e2 = __expf(dl * A2), e3 = __expf(dl * A3);
        h0 = e0 * h0 + du * bv.x; h1 = e1 * h1 + du * bv.y;
        h2 = e2 * h2 + du * bv.z; h3 = e3 * h3 + du * bv.w;
        p0 *= e0; p1 *= e1; p2 *= e2; p3 *= e3;
    }
    *(float4*)&Pl[g][4 * j] = make_float4(p0, p1, p2, p3);
    *(float4*)&Sl[g][4 * j] = make_float4(h0, h1, h2, h3);
    __syncthreads();
    // Kogge-Stone inclusive scan over SNC chunks
    for (int s = 1; s < SNC; s <<= 1) {
        float4 pp, sp;
        bool act = (g >= s);
        if (act) {
            pp = *(float4*)&Pl[g - s][4 * j];
            sp = *(float4*)&Sl[g - s][4 * j];
        }
        __syncthreads();
        if (act) {
            float4 pc = *(float4*)&Pl[g][4 * j];
            float4 sc = *(float4*)&Sl[g][4 * j];
            *(float4*)&Pl[g][4 * j] =
                make_float4(pp.x * pc.x, pp.y * pc.y, pp.z * pc.z, pp.w * pc.w);
            *(float4*)&Sl[g][4 * j] =
                make_float4(pc.x * sp.x + sc.x, pc.y * sp.y + sc.y,
                            pc.z * sp.z + sc.z, pc.w * sp.w + sc.w);
        }
        __syncthreads();
    }
    // phase C: replay with exclusive prefix; overwrite u_s with y
    float4 hv = make_float4(0.f, 0.f, 0.f, 0.f);
    if (g > 0) hv = *(const float4*)&Sl[g - 1][4 * j];
    float Dp = Ds[kd];
    h0 = hv.x; h1 = hv.y; h2 = hv.z; h3 = hv.w;
    for (int i = 0; i < SCH; ++i) {
        float dl = dl_s[lo + i], ul = u_s[lo + i];
        float4 bv = Bv[i * 4];
        float4 cv = Cv[i * 4];
        float du = dl * ul;
        float e0 = __expf(dl * A0), e1 = __expf(dl * A1);
        float e2 = __expf(dl * A2), e3 = __expf(dl * A3);
        h0 = e0 * h0 + du * bv.x; h1 = e1 * h1 + du * bv.y;
        h2 = e2 * h2 + du * bv.z; h3 = e3 * h3 + du * bv.w;
        float ps = h0 * cv.x + h1 * cv.y + h2 * cv.z + h3 * cv.w;
        ps += qxor1(ps);
        ps += qxor2(ps);
        if (j == 0) u_s[lo + i] = ps + Dp * ul;
    }
    __syncthreads();
    // coalesced writeout in ORIGINAL image coordinates (inverse map)
    float* yout = scan_y + kd * L_;
    for (int p = t; p < L_; p += 512) {
        int ll = (k & 1) ? (((p & 63) << 6) | (p >> 6)) : p;
        int sl = (k & 2) ? (L_ - 1 - ll) : ll;
        yout[p] = u_s[sl + (sl >> 6)];
    }
}

// K11: l-tile=16, grid=256 blocks, 256 threads = 16 groups x 16 lanes.
__global__ __launch_bounds__(256) void k_combine3(
        const float* __restrict__ scan_y, const float* __restrict__ onw,
        const float* __restrict__ onb, const float* __restrict__ xzT,
        const float* __restrict__ Wout, const float* __restrict__ x,
        const float* __restrict__ w2, const float* __restrict__ b2,
        float* __restrict__ x2, float* __restrict__ n2) {
    __shared__ float yt[16][196];
    __shared__ float red[16][16];
    int l0 = blockIdx.x * 16;
    int t = threadIdx.x;
    int l = t & 15, g = t >> 4;
    int d0 = g * 12;
    float psum = 0.f;
#pragma unroll
    for (int j = 0; j < 12; ++j) {
        int d = d0 + j;
        float y = scan_y[(0 * DI_ + d) * L_ + l0 + l]
                + scan_y[(1 * DI_ + d) * L_ + l0 + l]
                + scan_y[(2 * DI_ + d) * L_ + l0 + l]
                + scan_y[(3 * DI_ + d) * L_ + l0 + l];
        yt[l][d] = y;
        psum += y;
    }
    red[g][l] = psum;
    __syncthreads();
    float mu = 0.f;
#pragma unroll
    for (int g2 = 0; g2 < 16; ++g2) mu += red[g2][l];
    mu *= (1.f / DI_);
    float pv = 0.f;
#pragma unroll
    for (int j = 0; j < 12; ++j) {
        float yc = yt[l][d0 + j] - mu;
        pv += yc * yc;
    }
    __syncthreads();
    red[g][l] = pv;
    __syncthreads();
    float var = 0.f;
#pragma unroll
    for (int g2 = 0; g2 < 16; ++g2) var += red[g2][l];
    var *= (1.f / DI_);
    float rstd = rsqrtf(var + 1e-5f);
#pragma unroll
    for (int j = 0; j < 12; ++j) {
        int d = d0 + j;
        float zv = xzT[(DI_ + d) * L_ + l0 + l];
        float yn = (yt[l][d] - mu) * rstd * onw[d] + onb[d];
        yt[l][d] = yn * sp_silu(zv);
    }
    __syncthreads();
    int c0 = g * 6;
    float acc[6] = {0.f, 0.f, 0.f, 0.f, 0.f, 0.f};
    for (int dd = 0; dd < DI_; dd += 4) {
        float4 yv = *(const float4*)&yt[l][dd];
#pragma unroll
        for (int j = 0; j < 6; ++j) {
            float4 wv = *(const float4*)&Wout[(c0 + j) * DI_ + dd];
            acc[j] += yv.x * wv.x + yv.y * wv.y + yv.z * wv.z + yv.w * wv.w;
        }
    }
    float ss = 0.f;
    float x2v[6];
#pragma unroll
    for (int j = 0; j < 6; ++j) {
        int c = c0 + j;
        float v = x[c * L_ + l0 + l] + acc[j];
        x2v[j] = v; ss += v * v;
        x2[c * L_ + l0 + l] = v;
    }
    __syncthreads();
    red[g][l] = ss;
    __syncthreads();
    float tot = 0.f;
#pragma unroll
    for (int g2 = 0; g2 < 16; ++g2) tot += red[g2][l];
    float r2 = rsqrtf(tot * (1.f / C96) + 1e-6f);
#pragma unroll
    for (int j = 0; j < 6; ++j) {
        int c = c0 + j;
        n2[c * L_ + l0 + l] = x2v[j] * r2 * w2[c] + b2[c];
    }
}

// K13: depthwise 3x3 (no bias) on 510 channels + GELU(h1)*h2 gate.
__global__ void k_ffnconv(const float* __restrict__ hf, const float* __restrict__ w,
                          float* __restrict__ g) {
    int idx = blockIdx.x * 256 + threadIdx.x;
    if (idx >= HF_ * L_) return;
    int c = idx / L_, l = idx % L_;
    int h = l >> 6, wc = l & 63;
    float s1 = 0.f, s2 = 0.f;
#pragma unroll
    for (int di = -1; di <= 1; ++di)
#pragma unroll
        for (int dj = -1; dj <= 1; ++dj) {
            int hh = h + di, ww = wc + dj;
            if (hh >= 0 && hh < HW_ && ww >= 0 && ww < HW_) {
                int p = hh * HW_ + ww;
                int widx = (di + 1) * 3 + (dj + 1);
                s1 += hf[c * L_ + p] * w[c * 9 + widx];
                s2 += hf[(c + HF_) * L_ + p] * w[(c + HF_) * 9 + widx];
            }
        }
    float ge = 0.5f * s1 * (1.f + erff(s1 * 0.70710678118654752f));
    g[idx] = ge * s2;
}

// K14: pout GEMM + residual. grid (64, 4), 256 blocks. Full g tile in LDS.
__global__ __launch_bounds__(256) void k_pout3(const float* __restrict__ g,
        const float* __restrict__ W, const float* __restrict__ x2,
        float* __restrict__ out) {
    __shared__ float sg[HF_][64];
    int l0 = blockIdx.x * 64;
    int t = threadIdx.x;
    for (int i = t; i < HF_ * 64; i += 256) {
        int c = i >> 6, ll = i & 63;
        sg[c][ll] = g[c * L_ + l0 + ll];
    }
    __syncthreads();
    int l = t & 63, og = t >> 6;
    int c0 = blockIdx.y * 24 + og * 6;
    float acc[6] = {0.f, 0.f, 0.f, 0.f, 0.f, 0.f};
    for (int c = 0; c < HF_; ++c) {
        float v = sg[c][l];
#pragma unroll
        for (int j = 0; j < 6; ++j) acc[j] += v * W[(c0 + j) * HF_ + c];
    }
#pragma unroll
    for (int j = 0; j < 6; ++j) {
        int c = c0 + j;
        out[c * L_ + l0 + l] = x2[c * L_ + l0 + l] + acc[j];
    }
}

extern "C" void kernel_launch(void* const* d_in, const int* in_sizes, int n_in,
                              void* d_out, int out_size, void* d_ws, size_t ws_size,
                              hipStream_t stream) {
    const float* x         = (const float*)d_in[0];
    const float* norm1_w   = (const float*)d_in[1];
    const float* norm1_b   = (const float*)d_in[2];
    const float* in_proj_w = (const float*)d_in[3];
    const float* conv2d_w  = (const float*)d_in[4];
    const float* conv2d_b  = (const float*)d_in[5];
    const float* x_proj_w  = (const float*)d_in[6];
    const float* dt_projs_w= (const float*)d_in[7];
    const float* dt_projs_b= (const float*)d_in[8];
    const float* A_logs    = (const float*)d_in[9];
    const float* Ds        = (const float*)d_in[10];
    const float* out_norm_w= (const float*)d_in[11];
    const float* out_norm_b= (const float*)d_in[12];
    const float* out_proj_w= (const float*)d_in[13];
    const float* norm2_w   = (const float*)d_in[14];
    const float* norm2_b   = (const float*)d_in[15];
    const float* pin_w     = (const float*)d_in[16];
    const float* dw_w      = (const float*)d_in[17];
    const float* pout_w    = (const float*)d_in[18];

    float* ws = (float*)d_ws;
    float* n1     = ws; ws += C96 * L_;          // reused as dtsb after inproj
    float* xzT    = ws; ws += 2 * DI_ * L_;
    float* xconv  = ws; ws += DI_ * L_;
    float* xs     = ws; ws += Kk * DI_ * L_;     // reused as hf after scan
    float* gbuf   = ws; ws += Kk * DI_ * L_;     // (ex-delta slot) ffn gate buf
    float* BsT    = ws; ws += Kk * L_ * Nn;
    float* CsT    = ws; ws += Kk * L_ * Nn;
    float* scan_y = ws; ws += Kk * DI_ * L_;
    float* x2     = ws; ws += C96 * L_;
    float* n2     = ws; ws += C96 * L_;
    float* dtsb   = n1;
    float* hf     = xs;

    k_rmsln1<<<256, 256, 0, stream>>>(x, norm1_w, norm1_b, n1);
    k_fc96<<<dim3(64, 6), 256, 0, stream>>>(n1, in_proj_w, xzT, 2 * DI_);
    k_conv192<<<3072, 256, 0, stream>>>(xzT, conv2d_w, conv2d_b, xconv);
    k_build_xs<<<12288, 256, 0, stream>>>(xconv, xs);
    k_xdbl2<<<dim3(64, 4), 256, 0, stream>>>(xs, x_proj_w, dtsb, BsT, CsT);
    k_scan<<<768, 512, 0, stream>>>(dtsb, dt_projs_w, dt_projs_b, xs, BsT, CsT,
                                    A_logs, Ds, scan_y);
    k_combine3<<<256, 256, 0, stream>>>(scan_y, out_norm_w, out_norm_b, xzT,
                                        out_proj_w, x, norm2_w, norm2_b, x2, n2);
    k_fc96<<<dim3(64, 8), 256, 0, stream>>>(n2, pin_w, hf, 2 * HF_);
    k_ffnconv<<<4080, 256, 0, stream>>>(hf, dw_w, gbuf);
    k_pout3<<<dim3(64, 4), 256, 0, stream>>>(gbuf, pout_w, x2, (float*)d_out);
}